// Round 4
// baseline (695.506 us; speedup 1.0000x reference)
//
#include <hip/hip_runtime.h>
#include <math.h>

#define NPCH 49
#define NA 18
#define NB 8192
#define TOTAL (NB*NPCH)    // 401408

typedef __attribute__((ext_vector_type(8))) short bf16x8;
typedef __attribute__((ext_vector_type(4))) float f32x4;

__device__ __forceinline__ unsigned short f2bf(float f) {
    unsigned int u = __float_as_uint(f);
    return (unsigned short)((u + 0x7FFFu + ((u >> 16) & 1u)) >> 16);
}

// Frag-major bf16 weight buffer (ushort units). Frag = 512 ushort = one
// 16x32 (n x k) A-tile of W^T: entry ((s*NT+nt)*64 + lane)*8 + j holds
// W[k = s*32 + (lane>>4)*8 + j][n = nt*16 + (lane&15)].
#define W1_OFF  0          // e1: 9s x 16nt  (K=288, N=256)
#define W2_OFF  73728      // e2: 8s x 8nt   (K=256, N=128)
#define W3_OFF  106496     // e3: 4s x 2nt   (K=128, N=32, n>=18 zero)
#define WA1_OFF 110592     // a1: 5s x 4nt   (K=160 shifted: k<16 zero, else Wa1[k-16])
#define WA2_OFF 120832     // a2: 2s x 4nt   (K=64,  N=64)
#define W_TOTAL 124928

__global__ __launch_bounds__(256)
void prep_weights(const float* __restrict__ We1, const float* __restrict__ We2,
                  const float* __restrict__ We3, const float* __restrict__ Wa1,
                  const float* __restrict__ Wa2, unsigned short* __restrict__ wb)
{
    int i = blockIdx.x * 256 + threadIdx.x;
    if (i >= W_TOTAL) return;
    int idx = i;
    float v;
    if (idx < 73728) {                       // W1f
        int frag = idx >> 9, l = (idx >> 3) & 63, j = idx & 7;
        int s = frag >> 4, nt = frag & 15;
        int n = nt * 16 + (l & 15), k = s * 32 + ((l >> 4) << 3) + j;
        v = We1[k * 256 + n];
    } else if ((idx -= 73728) < 32768) {     // W2f
        int frag = idx >> 9, l = (idx >> 3) & 63, j = idx & 7;
        int s = frag >> 3, nt = frag & 7;
        int n = nt * 16 + (l & 15), k = s * 32 + ((l >> 4) << 3) + j;
        v = We2[k * 128 + n];
    } else if ((idx -= 32768) < 4096) {      // W3f (N padded to 32)
        int frag = idx >> 9, l = (idx >> 3) & 63, j = idx & 7;
        int s = frag >> 1, nt = frag & 1;
        int n = nt * 16 + (l & 15), k = s * 32 + ((l >> 4) << 3) + j;
        v = (n < NA) ? We3[k * NA + n] : 0.0f;
    } else if ((idx -= 4096) < 10240) {      // WA1f (K=160, k<16 zero-pad)
        int frag = idx >> 9, l = (idx >> 3) & 63, j = idx & 7;
        int s = frag >> 2, nt = frag & 3;
        int n = nt * 16 + (l & 15), k = s * 32 + ((l >> 4) << 3) + j;
        v = (k >= 16) ? Wa1[(k - 16) * 64 + n] : 0.0f;
    } else {                                 // WA2f
        idx -= 10240;
        int frag = idx >> 9, l = (idx >> 3) & 63, j = idx & 7;
        int s = frag >> 2, nt = frag & 3;
        int n = nt * 16 + (l & 15), k = s * 32 + ((l >> 4) << 3) + j;
        v = Wa2[k * 64 + n];
    }
    wb[i] = f2bf(v);
}

// ---------------------------------------------------------------------------
// C->B fragment conversion (transposed chain): given two consecutive output
// tiles (f32x4 each, rows n = 16t + 4hi + r, col m), apply relu, pack to
// bf16, and redistribute so this lane holds B[k = 32s'+8hi+j][m] (j=0..7).
// dest word w <- u(w&1) of lane 32*(hi&1) + 16*(w>>1) + m, tile 2s'+(hi>>1).
// ---------------------------------------------------------------------------
__device__ __forceinline__ bf16x8 conv_frag(f32x4 a, f32x4 b, int hi, int m)
{
    unsigned u0a, u1a, u0b, u1b;
    float a0 = fmaxf(a[0], 0.f), a1 = fmaxf(a[1], 0.f);
    float a2 = fmaxf(a[2], 0.f), a3 = fmaxf(a[3], 0.f);
    float b0 = fmaxf(b[0], 0.f), b1 = fmaxf(b[1], 0.f);
    float b2 = fmaxf(b[2], 0.f), b3 = fmaxf(b[3], 0.f);
    asm("v_cvt_pk_bf16_f32 %0, %1, %2" : "=v"(u0a) : "v"(a0), "v"(a1));
    asm("v_cvt_pk_bf16_f32 %0, %1, %2" : "=v"(u1a) : "v"(a2), "v"(a3));
    asm("v_cvt_pk_bf16_f32 %0, %1, %2" : "=v"(u0b) : "v"(b0), "v"(b1));
    asm("v_cvt_pk_bf16_f32 %0, %1, %2" : "=v"(u1b) : "v"(b2), "v"(b3));
    const int sA = ((hi & 1) << 5) + m;
    const int sB = sA + 16;
    int w0a = __shfl((int)u0a, sA, 64), w1a = __shfl((int)u1a, sA, 64);
    int w2a = __shfl((int)u0a, sB, 64), w3a = __shfl((int)u1a, sB, 64);
    int w0b = __shfl((int)u0b, sA, 64), w1b = __shfl((int)u1b, sA, 64);
    int w2b = __shfl((int)u0b, sB, 64), w3b = __shfl((int)u1b, sB, 64);
    union { int w[4]; bf16x8 v; } r;
    const bool lo = (hi < 2);
    r.w[0] = lo ? w0a : w0b;  r.w[1] = lo ? w1a : w1b;
    r.w[2] = lo ? w2a : w2b;  r.w[3] = lo ? w3a : w3b;
    return r.v;
}

__device__ __forceinline__ f32x4 ld_bias4(const float* p) {
    const float4 b = *(const float4*)p;
    return (f32x4){b.x, b.y, b.z, b.w};
}

// ---------------------------------------------------------------------------
// Fused kernel, transposed register-resident chain. 1 block = 1 image,
// 4 waves x 16 patches. ONE barrier (after patch-major staging).
// PM stride 296 ushort: 16B-aligned b128 frag reads, <=2-way bank conflicts.
// ---------------------------------------------------------------------------
#define PMS 296
__global__ __launch_bounds__(256)
void fused_mfma_kernel(const float* __restrict__ last_s, const float* __restrict__ now_s,
                       const unsigned short* __restrict__ wb,
                       const float* __restrict__ be1, const float* __restrict__ be2,
                       const float* __restrict__ be3, const float* __restrict__ ba1,
                       const float* __restrict__ ba2, const float* __restrict__ ba3,
                       const float* __restrict__ Wa3,
                       float* __restrict__ out_each, float* __restrict__ ws_alpha)
{
    __shared__ __align__(16) unsigned short PM[64 * PMS];   // 37888 B

    const int t    = threadIdx.x;
    const int lane = t & 63;
    const int wid  = t >> 6;
    const int hi   = lane >> 4;
    const int m    = lane & 15;
    const int img  = blockIdx.x;
    const int p    = wid * 16 + m;     // patch owned by this lane column

    // ---- phase 0: coalesced image read -> patch-major LDS (diff | now) ----
    {
        const float* nowI  = now_s  + (size_t)img * 7056;
        const float* lastI = last_s + (size_t)img * 7056;
        for (int i = t; i < 1764; i += 256) {
            const float4 n4 = *(const float4*)(nowI + i * 4);
            const float4 l4 = *(const float4*)(lastI + i * 4);
            const int px  = i * 4;
            const int row = px / 84;
            const int col = px - row * 84;
            const int pi = row / 12, pj = col / 12;
            const int fr = row - pi * 12, fc = col - pj * 12;
            const int pp = pi * 7 + pj;
            const int f  = fr * 12 + fc;
            const float k255 = 1.0f / 255.0f;
            float d0 = (n4.x - l4.x) * k255, d1 = (n4.y - l4.y) * k255;
            float d2 = (n4.z - l4.z) * k255, d3 = (n4.w - l4.w) * k255;
            float w0 = n4.x * k255, w1 = n4.y * k255;
            float w2 = n4.z * k255, w3 = n4.w * k255;
            unsigned dlo, dhi2, wlo, whi2;
            asm("v_cvt_pk_bf16_f32 %0, %1, %2" : "=v"(dlo)  : "v"(d0), "v"(d1));
            asm("v_cvt_pk_bf16_f32 %0, %1, %2" : "=v"(dhi2) : "v"(d2), "v"(d3));
            asm("v_cvt_pk_bf16_f32 %0, %1, %2" : "=v"(wlo)  : "v"(w0), "v"(w1));
            asm("v_cvt_pk_bf16_f32 %0, %1, %2" : "=v"(whi2) : "v"(w2), "v"(w3));
            *(uint2*)(PM + pp * PMS + f)       = (uint2){dlo, dhi2};
            *(uint2*)(PM + pp * PMS + 144 + f) = (uint2){wlo, whi2};
        }
        // zero pad rows 49..63 (so wave 3's dead lanes feed zeros, not stale LDS)
        for (int i = t; i < 1110; i += 256)
            *(uint2*)(PM + 49 * PMS + i * 4) = (uint2){0u, 0u};
    }
    __syncthreads();   // the only barrier

    const unsigned short* Xrow = PM + p * PMS;

    // ---- alpha chain: a1 (K=160 over features 128..287) -> a2 -> a3 ----
    {
        f32x4 accA[4];
        #pragma unroll
        for (int nt = 0; nt < 4; ++nt) accA[nt] = ld_bias4(ba1 + nt * 16 + 4 * hi);
        const unsigned short* wa1b = wb + WA1_OFF + lane * 8;
        #pragma unroll
        for (int s = 0; s < 5; ++s) {
            const bf16x8 xf = *(const bf16x8*)(Xrow + (s + 4) * 32 + hi * 8);
            #pragma unroll
            for (int nt = 0; nt < 4; ++nt) {
                const bf16x8 wf = *(const bf16x8*)(wa1b + (s * 4 + nt) * 512);
                accA[nt] = __builtin_amdgcn_mfma_f32_16x16x32_bf16(wf, xf, accA[nt], 0, 0, 0);
            }
        }
        f32x4 accB[4];
        #pragma unroll
        for (int nt = 0; nt < 4; ++nt) accB[nt] = ld_bias4(ba2 + nt * 16 + 4 * hi);
        const unsigned short* wa2b = wb + WA2_OFF + lane * 8;
        #pragma unroll
        for (int s = 0; s < 2; ++s) {
            const bf16x8 hf = conv_frag(accA[2 * s], accA[2 * s + 1], hi, m);
            #pragma unroll
            for (int nt = 0; nt < 4; ++nt) {
                const bf16x8 wf = *(const bf16x8*)(wa2b + (s * 4 + nt) * 512);
                accB[nt] = __builtin_amdgcn_mfma_f32_16x16x32_bf16(wf, hf, accB[nt], 0, 0, 0);
            }
        }
        float part = 0.0f;
        #pragma unroll
        for (int tt = 0; tt < 4; ++tt) {
            const float4 w3 = *(const float4*)(Wa3 + tt * 16 + 4 * hi);
            part += fmaxf(accB[tt][0], 0.f) * w3.x + fmaxf(accB[tt][1], 0.f) * w3.y +
                    fmaxf(accB[tt][2], 0.f) * w3.z + fmaxf(accB[tt][3], 0.f) * w3.w;
        }
        part += __shfl_xor(part, 16, 64);
        part += __shfl_xor(part, 32, 64);
        if (hi == 0 && p < NPCH) ws_alpha[img * NPCH + p] = part + ba3[0];
    }

    // ---- e1: K=288 -> N=256 ----
    f32x4 acc[16];
    #pragma unroll
    for (int nt = 0; nt < 16; ++nt) acc[nt] = ld_bias4(be1 + nt * 16 + 4 * hi);
    {
        const unsigned short* w1b = wb + W1_OFF + lane * 8;
        for (int s = 0; s < 9; ++s) {
            const bf16x8 xf = *(const bf16x8*)(Xrow + s * 32 + hi * 8);
            const unsigned short* wp = w1b + s * 16 * 512;
            #pragma unroll
            for (int nt = 0; nt < 16; ++nt) {
                const bf16x8 wf = *(const bf16x8*)(wp + nt * 512);
                acc[nt] = __builtin_amdgcn_mfma_f32_16x16x32_bf16(wf, xf, acc[nt], 0, 0, 0);
            }
        }
    }

    // ---- e2: K=256 -> N=128 (in-register conversion, no LDS) ----
    f32x4 acc2[8];
    #pragma unroll
    for (int nt = 0; nt < 8; ++nt) acc2[nt] = ld_bias4(be2 + nt * 16 + 4 * hi);
    {
        const unsigned short* w2b = wb + W2_OFF + lane * 8;
        #pragma unroll
        for (int s2 = 0; s2 < 8; ++s2) {
            const bf16x8 hf = conv_frag(acc[2 * s2], acc[2 * s2 + 1], hi, m);
            #pragma unroll
            for (int nt = 0; nt < 8; ++nt) {
                const bf16x8 wf = *(const bf16x8*)(w2b + (s2 * 8 + nt) * 512);
                acc2[nt] = __builtin_amdgcn_mfma_f32_16x16x32_bf16(wf, hf, acc2[nt], 0, 0, 0);
            }
        }
    }

    // ---- e3: K=128 -> N=32 (18 valid) + log_softmax over actions ----
    {
        f32x4 a3_0 = ld_bias4(be3 + 4 * hi);   // n = 4hi..4hi+3 (<16, all valid bias)
        f32x4 a3_1 = (hi == 0) ? (f32x4){be3[16], be3[17], 0.f, 0.f}
                               : (f32x4){0.f, 0.f, 0.f, 0.f};
        const unsigned short* w3b = wb + W3_OFF + lane * 8;
        #pragma unroll
        for (int s3 = 0; s3 < 4; ++s3) {
            const bf16x8 hf = conv_frag(acc2[2 * s3], acc2[2 * s3 + 1], hi, m);
            const bf16x8 wf0 = *(const bf16x8*)(w3b + (s3 * 2 + 0) * 512);
            const bf16x8 wf1 = *(const bf16x8*)(w3b + (s3 * 2 + 1) * 512);
            a3_0 = __builtin_amdgcn_mfma_f32_16x16x32_bf16(wf0, hf, a3_0, 0, 0, 0);
            a3_1 = __builtin_amdgcn_mfma_f32_16x16x32_bf16(wf1, hf, a3_1, 0, 0, 0);
        }
        const float v0 = a3_0[0], v1 = a3_0[1], v2 = a3_0[2], v3 = a3_0[3];
        const float x16 = a3_1[0], x17 = a3_1[1];
        float mx = fmaxf(fmaxf(v0, v1), fmaxf(v2, v3));
        if (hi == 0) mx = fmaxf(mx, fmaxf(x16, x17));
        mx = fmaxf(mx, __shfl_xor(mx, 16, 64));
        mx = fmaxf(mx, __shfl_xor(mx, 32, 64));
        float se = expf(v0 - mx) + expf(v1 - mx) + expf(v2 - mx) + expf(v3 - mx);
        if (hi == 0) se += expf(x16 - mx) + expf(x17 - mx);
        se += __shfl_xor(se, 16, 64);
        se += __shfl_xor(se, 32, 64);
        const float L = mx + logf(se);
        if (p < NPCH) {
            float* o = out_each + (size_t)(img * NPCH + p) * NA;
            o[4 * hi + 0] = v0 - L;
            o[4 * hi + 1] = v1 - L;
            o[4 * hi + 2] = v2 - L;
            o[4 * hi + 3] = v3 - L;
            if (hi == 0) { o[16] = x16 - L; o[17] = x17 - L; }
        }
    }
}

// ---------------------------------------------------------------------------
// Kernel B: one wave per batch element (unchanged, validated).
// ---------------------------------------------------------------------------
__global__ __launch_bounds__(64)
void alpha_combine_kernel(const float* __restrict__ ws_alpha,
                          const float* __restrict__ out_each,
                          float* __restrict__ out_probs,
                          float* __restrict__ ws_ent)
{
    const int b = blockIdx.x;
    const int lane = threadIdx.x;

    float lg = (lane < NPCH) ? ws_alpha[b * NPCH + lane] : -3.0e38f;
    float m = lg;
    #pragma unroll
    for (int off = 32; off > 0; off >>= 1) m = fmaxf(m, __shfl_xor(m, off, 64));
    float ex = (lane < NPCH) ? expf(lg - m) : 0.0f;
    float s = ex;
    #pragma unroll
    for (int off = 32; off > 0; off >>= 1) s += __shfl_xor(s, off, 64);
    const float ls = logf(s);
    const float alpha = ex / s;

    float ent = (lane < NPCH) ? alpha * (lg - m - ls) : 0.0f;
    #pragma unroll
    for (int off = 32; off > 0; off >>= 1) ent += __shfl_xor(ent, off, 64);
    if (lane == 0) ws_ent[b] = ent;

    float acc = 0.0f;
    const float* eb = out_each + (size_t)b * NPCH * NA;
    for (int p = 0; p < NPCH; ++p) {
        const float ap = __shfl(alpha, p, 64);
        if (lane < NA) acc += ap * eb[p * NA + lane];
    }
    float mm = (lane < NA) ? acc : -3.0e38f;
    #pragma unroll
    for (int off = 32; off > 0; off >>= 1) mm = fmaxf(mm, __shfl_xor(mm, off, 64));
    float ee = (lane < NA) ? expf(acc - mm) : 0.0f;
    #pragma unroll
    for (int off = 32; off > 0; off >>= 1) ee += __shfl_xor(ee, off, 64);
    if (lane < NA) out_probs[b * NA + lane] = acc - mm - logf(ee);
}

__global__ __launch_bounds__(256)
void ent_reduce_kernel(const float* __restrict__ ws_ent, float* __restrict__ out_scalar)
{
    float s = 0.0f;
    for (int i = threadIdx.x; i < NB; i += 256) s += ws_ent[i];
    #pragma unroll
    for (int off = 32; off > 0; off >>= 1) s += __shfl_xor(s, off, 64);
    __shared__ float ps[4];
    if ((threadIdx.x & 63) == 0) ps[threadIdx.x >> 6] = s;
    __syncthreads();
    if (threadIdx.x == 0)
        out_scalar[0] = (ps[0] + ps[1] + ps[2] + ps[3]) * (1.0f / NB);
}

extern "C" void kernel_launch(void* const* d_in, const int* in_sizes, int n_in,
                              void* d_out, int out_size, void* d_ws, size_t ws_size,
                              hipStream_t stream)
{
    (void)in_sizes; (void)n_in; (void)out_size; (void)ws_size;

    const float* last_s = (const float*)d_in[0];
    const float* now_s  = (const float*)d_in[1];
    const float* We1 = (const float*)d_in[2];  const float* be1 = (const float*)d_in[3];
    const float* We2 = (const float*)d_in[4];  const float* be2 = (const float*)d_in[5];
    const float* We3 = (const float*)d_in[6];  const float* be3 = (const float*)d_in[7];
    const float* Wa1 = (const float*)d_in[8];  const float* ba1 = (const float*)d_in[9];
    const float* Wa2 = (const float*)d_in[10]; const float* ba2 = (const float*)d_in[11];
    const float* Wa3 = (const float*)d_in[12]; const float* ba3 = (const float*)d_in[13];

    float* out = (float*)d_out;
    float* out_probs = out;                    // [B,18]
    float* out_ent   = out + NB * NA;          // scalar
    float* out_each  = out + NB * NA + 1;      // [B,49,18]

    float* ws_alpha = (float*)d_ws;            // [TOTAL]
    float* ws_ent   = ws_alpha + TOTAL;        // [NB]
    unsigned short* wbuf = (unsigned short*)(ws_ent + NB);  // frag-major bf16 weights

    prep_weights<<<dim3((W_TOTAL + 255) / 256), dim3(256), 0, stream>>>(
        We1, We2, We3, Wa1, Wa2, wbuf);

    fused_mfma_kernel<<<dim3(NB), dim3(256), 0, stream>>>(
        last_s, now_s, wbuf, be1, be2, be3, ba1, ba2, ba3, Wa3,
        out_each, ws_alpha);

    alpha_combine_kernel<<<dim3(NB), dim3(64), 0, stream>>>(
        ws_alpha, out_each, out_probs, ws_ent);

    ent_reduce_kernel<<<dim3(1), dim3(256), 0, stream>>>(ws_ent, out_ent);
}

// Round 5
// 400.309 us; speedup vs baseline: 1.7374x; 1.7374x over previous
//
#include <hip/hip_runtime.h>
#include <math.h>

#define NPCH 49
#define NA 18
#define NB 8192
#define TOTAL (NB*NPCH)    // 401408

typedef __attribute__((ext_vector_type(8))) short bf16x8;
typedef __attribute__((ext_vector_type(4))) float f32x4;

__device__ __forceinline__ unsigned short f2bf(float f) {
    unsigned int u = __float_as_uint(f);
    return (unsigned short)((u + 0x7FFFu + ((u >> 16) & 1u)) >> 16);
}

__device__ __forceinline__ void g2lds16(const void* g, void* l) {
    __builtin_amdgcn_global_load_lds(
        (const __attribute__((address_space(1))) unsigned int*)g,
        (__attribute__((address_space(3))) unsigned int*)l, 16, 0, 0);
}

// ---------------------------------------------------------------------------
// Weight stream: 256 frags x 512 ushort (1KB each), consumption order, chunk =
// 8 frags = 8KB. Frag fs element (l, j): value W[k0+ (l>>4)*8 + j][n0 + (l&15)]
//  fs   0..19 : a1  s=fs>>2, w=fs&3      (k<144 ? Wa1 : 0)   n0=w*16
//  fs  20..27 : a2  s=(fs-20)>>2, w=&3                        n0=w*16
//  fs  28..31 : zero pad
//  fs  32..175: e1  q=fs-32: s=q>>4, nt=(q>>2)&3, w=q&3       n0=w*64+nt*16
//  fs 176..239: e2  q=fs-176: s=q>>3, nt=(q>>2)&1, w=q&3      n0=w*32+nt*16
//  fs 240..247: e3  q=fs-240: s=q>>1, nt=q&1                  n0=nt*16 (n>=18 ->0)
//  fs 248..255: zero pad
// ---------------------------------------------------------------------------
#define WS_US (256*512)   // 131072 ushorts = 256KB

__global__ __launch_bounds__(256)
void prep_weights(const float* __restrict__ We1, const float* __restrict__ We2,
                  const float* __restrict__ We3, const float* __restrict__ Wa1,
                  const float* __restrict__ Wa2, unsigned short* __restrict__ wst)
{
    int i = blockIdx.x * 256 + threadIdx.x;
    if (i >= WS_US) return;
    const int fs = i >> 9, l = (i >> 3) & 63, j = i & 7;
    const int kh = ((l >> 4) << 3) + j;
    const int nl = l & 15;
    float v = 0.0f;
    if (fs < 20) {
        int s = fs >> 2, w = fs & 3;
        int k = s * 32 + kh, n = w * 16 + nl;
        v = (k < 144) ? Wa1[k * 64 + n] : 0.0f;
    } else if (fs < 28) {
        int q = fs - 20, s = q >> 2, w = q & 3;
        v = Wa2[(s * 32 + kh) * 64 + (w * 16 + nl)];
    } else if (fs < 32) {
        v = 0.0f;
    } else if (fs < 176) {
        int q = fs - 32, s = q >> 4, nt = (q >> 2) & 3, w = q & 3;
        v = We1[(s * 32 + kh) * 256 + (w * 64 + nt * 16 + nl)];
    } else if (fs < 240) {
        int q = fs - 176, s = q >> 3, nt = (q >> 2) & 1, w = q & 3;
        v = We2[(s * 32 + kh) * 128 + (w * 32 + nt * 16 + nl)];
    } else if (fs < 248) {
        int q = fs - 240, s = q >> 1, nt = q & 1;
        int n = nt * 16 + nl;
        v = (n < NA) ? We3[(s * 32 + kh) * NA + n] : 0.0f;
    }
    wst[i] = f2bf(v);
}

// ---------------------------------------------------------------------------
// Fused kernel: 1 block = 1 image, 4 waves, R2's N-split MFMA phases; weights
// flow through a 16KB LDS double-buffer staged 1 chunk ahead via
// global_load_lds (latency hidden under compute).
// LDS map (bytes, total 69184, 2 blocks/CU):
//   Ein [0,40960) | IMG [40960,69184) (phases 0-1 only)
//   after Ein build: DB dbuf [40960,57344) | HA1 [57344,65536) | APT [65536,66560)
//   H1 [0,32768) overlays Ein after e1; H2 split: mt0,1 [32768,40960),
//   mt2,3 [57344,65536) (HA1 dead by then)
// ---------------------------------------------------------------------------
__global__ __launch_bounds__(256)
void fused_mfma_kernel(const float* __restrict__ last_s, const float* __restrict__ now_s,
                       const unsigned short* __restrict__ wstream,
                       const float* __restrict__ be1, const float* __restrict__ be2,
                       const float* __restrict__ be3, const float* __restrict__ ba1,
                       const float* __restrict__ ba2, const float* __restrict__ ba3,
                       const float* __restrict__ Wa3,
                       float* __restrict__ out_each, float* __restrict__ ws_alpha)
{
    __shared__ __align__(16) unsigned char smem[69184];
    unsigned short* Ein = (unsigned short*)smem;
    unsigned short* IMG = (unsigned short*)(smem + 40960);
    unsigned short* H1  = (unsigned short*)smem;
    unsigned short* DB  = (unsigned short*)(smem + 40960);  // [2][4096] us
    unsigned short* HA1 = (unsigned short*)(smem + 57344);
    unsigned short* SM16= (unsigned short*)smem;            // ushort view of smem
    float*          APT = (float*)(smem + 65536);           // [4][64]

    const int t    = threadIdx.x;
    const int lane = t & 63;
    const int wid  = t >> 6;
    const int g    = lane >> 4;
    const int rl   = lane & 15;
    const int img  = blockIdx.x;

#define WFRAG(fs) (*(const bf16x8*)(DB + (((fs) >> 3) & 1) * 4096 + ((fs) & 7) * 512 + lane * 8))
#define STAGE(ck) do { \
    const unsigned char* _s = (const unsigned char*)wstream + (size_t)(ck) * 8192 + wid * 2048 + lane * 16; \
    unsigned char* _d = (unsigned char*)smem + 40960 + ((ck) & 1) * 8192 + wid * 2048; \
    g2lds16(_s, _d); g2lds16(_s + 1024, _d + 1024); \
} while (0)
#define ADV(ck) do { __syncthreads(); if ((ck) + 2 <= 30) STAGE((ck) + 2); } while (0)

    // ---- phase 0: coalesced image load -> IMG bf16 (diff | now) ----
    {
        const float* nowI  = now_s  + (size_t)img * 7056;
        const float* lastI = last_s + (size_t)img * 7056;
        for (int i = t; i < 1764; i += 256) {
            const float4 n4 = *(const float4*)(nowI + i * 4);
            const float4 l4 = *(const float4*)(lastI + i * 4);
            ushort4 d4, w4;
            d4.x = f2bf((n4.x - l4.x) * (1.0f / 255.0f));
            d4.y = f2bf((n4.y - l4.y) * (1.0f / 255.0f));
            d4.z = f2bf((n4.z - l4.z) * (1.0f / 255.0f));
            d4.w = f2bf((n4.w - l4.w) * (1.0f / 255.0f));
            w4.x = f2bf(n4.x * (1.0f / 255.0f));
            w4.y = f2bf(n4.y * (1.0f / 255.0f));
            w4.z = f2bf(n4.z * (1.0f / 255.0f));
            w4.w = f2bf(n4.w * (1.0f / 255.0f));
            *(ushort4*)(IMG + i * 4)        = d4;
            *(ushort4*)(IMG + 7056 + i * 4) = w4;
        }
    }
    __syncthreads();

    // ---- phase 1: build Ein A-fragments from IMG ----
    {
        const int p = wid * 16 + rl;
        const bf16x8 z = {0, 0, 0, 0, 0, 0, 0, 0};
        *(bf16x8*)(Ein + (wid * 10 + 9) * 512 + lane * 8) = z;   // zero pad slot
        if (p < NPCH) {
            const int pi = p / 7, pj = p - pi * 7;
            const int pbase = pi * 1008 + pj * 12;
            #pragma unroll
            for (int s = 0; s < 9; ++s) {
                union { unsigned short u[8]; bf16x8 v; } pk;
                #pragma unroll
                for (int j = 0; j < 8; ++j) {
                    const int k   = s * 32 + g * 8 + j;
                    const int sel = (k >= 144) ? 1 : 0;
                    const int f   = k - sel * 144;
                    const int fr  = f / 12, fc = f - fr * 12;
                    pk.u[j] = IMG[sel * 7056 + pbase + fr * 84 + fc];
                }
                *(bf16x8*)(Ein + (wid * 10 + s) * 512 + lane * 8) = pk.v;
            }
        } else {
            #pragma unroll
            for (int s = 0; s < 9; ++s)
                *(bf16x8*)(Ein + (wid * 10 + s) * 512 + lane * 8) = z;
        }
    }
    __syncthreads();          // IMG dead -> DB/HA1/APT regions valid

    STAGE(0); STAGE(1);
    __syncthreads();          // chunks 0,1 resident

    // ================= alpha layer 1: 144(->160) -> 64 =================
    const int colA = wid * 16 + rl;
    f32x4 accA[4];
    {
        const float b1 = ba1[colA];
        #pragma unroll
        for (int mt = 0; mt < 4; ++mt) accA[mt] = (f32x4){b1, b1, b1, b1};
    }
#define A1_STEP(sa) do { \
    const bf16x8 bfr = WFRAG((sa) * 4 + wid); \
    const int ok = 144 + (sa) * 32 + g * 8; \
    _Pragma("unroll") \
    for (int mt = 0; mt < 4; ++mt) { \
        const bf16x8 af = *(const bf16x8*)(Ein + (mt * 10 + (ok >> 5)) * 512 + \
                                           ((ok >> 3) & 3) * 128 + rl * 8); \
        accA[mt] = __builtin_amdgcn_mfma_f32_16x16x32_bf16(af, bfr, accA[mt], 0, 0, 0); \
    } \
} while (0)

    A1_STEP(0); A1_STEP(1);
    ADV(0);
    A1_STEP(2); A1_STEP(3);
    ADV(1);
    A1_STEP(4);
    // HA1 fragment writes (relu)
    {
        const int sA  = wid >> 1;
        const int hiA = (wid & 1) * 2 + (rl >> 3);
        const int jA  = rl & 7;
        #pragma unroll
        for (int mt = 0; mt < 4; ++mt) {
            unsigned short* base = HA1 + (mt * 2 + sA) * 512 + hiA * 128 + g * 32 + jA;
            #pragma unroll
            for (int r = 0; r < 4; ++r)
                base[r * 8] = f2bf(fmaxf(accA[mt][r], 0.0f));
        }
    }
    __syncthreads();   // HA1 visible (also drains chunk-3 staging; harmless)

    // ================= alpha layer 2 + fused layer 3 =================
    {
        const float b2 = ba2[colA];
        const float w3 = Wa3[colA];
        f32x4 accB[4];
        #pragma unroll
        for (int mt = 0; mt < 4; ++mt) accB[mt] = (f32x4){b2, b2, b2, b2};
        // s = 0 (chunk 2)
        {
            const bf16x8 bfr = WFRAG(20 + wid);
            #pragma unroll
            for (int mt = 0; mt < 4; ++mt) {
                const bf16x8 af = *(const bf16x8*)(HA1 + (mt * 2 + 0) * 512 + lane * 8);
                accB[mt] = __builtin_amdgcn_mfma_f32_16x16x32_bf16(af, bfr, accB[mt], 0, 0, 0);
            }
        }
        ADV(2);
        // s = 1 (chunk 3)
        {
            const bf16x8 bfr = WFRAG(24 + wid);
            #pragma unroll
            for (int mt = 0; mt < 4; ++mt) {
                const bf16x8 af = *(const bf16x8*)(HA1 + (mt * 2 + 1) * 512 + lane * 8);
                accB[mt] = __builtin_amdgcn_mfma_f32_16x16x32_bf16(af, bfr, accB[mt], 0, 0, 0);
            }
        }
        #pragma unroll
        for (int mt = 0; mt < 4; ++mt) {
            #pragma unroll
            for (int r = 0; r < 4; ++r) {
                float v = fmaxf(accB[mt][r], 0.0f) * w3;
                v += __shfl_xor(v, 1); v += __shfl_xor(v, 2);
                v += __shfl_xor(v, 4); v += __shfl_xor(v, 8);
                if (rl == 0) APT[wid * 64 + mt * 16 + g * 4 + r] = v;
            }
        }
    }
    __syncthreads();
    if (t < NPCH)
        ws_alpha[img * NPCH + t] = APT[t] + APT[64 + t] + APT[128 + t] + APT[192 + t] + ba3[0];
    ADV(3);

    // ================= e layer 1: 288 -> 256 =================
    f32x4 acc1[4][4];
    #pragma unroll
    for (int nt = 0; nt < 4; ++nt) {
        const float b = be1[wid * 64 + nt * 16 + rl];
        #pragma unroll
        for (int mt = 0; mt < 4; ++mt) acc1[mt][nt] = (f32x4){b, b, b, b};
    }
    for (int s = 0; s < 9; ++s) {
        bf16x8 xfr[4];
        #pragma unroll
        for (int mt = 0; mt < 4; ++mt)
            xfr[mt] = *(const bf16x8*)(Ein + (mt * 10 + s) * 512 + lane * 8);
        // half A: nt 0,1 (chunk 4+2s)
        #pragma unroll
        for (int nt = 0; nt < 2; ++nt) {
            const bf16x8 bfr = WFRAG(32 + s * 16 + nt * 4 + wid);
            #pragma unroll
            for (int mt = 0; mt < 4; ++mt)
                acc1[mt][nt] = __builtin_amdgcn_mfma_f32_16x16x32_bf16(xfr[mt], bfr, acc1[mt][nt], 0, 0, 0);
        }
        ADV(4 + 2 * s);
        // half B: nt 2,3 (chunk 5+2s)
        #pragma unroll
        for (int nt = 2; nt < 4; ++nt) {
            const bf16x8 bfr = WFRAG(32 + s * 16 + nt * 4 + wid);
            #pragma unroll
            for (int mt = 0; mt < 4; ++mt)
                acc1[mt][nt] = __builtin_amdgcn_mfma_f32_16x16x32_bf16(xfr[mt], bfr, acc1[mt][nt], 0, 0, 0);
        }
        ADV(5 + 2 * s);   // s=8: sync doubles as "all Ein reads done" barrier
    }

    // H1 fragment writes (relu), overlaying Ein
    {
        #pragma unroll
        for (int mt = 0; mt < 4; ++mt) {
            #pragma unroll
            for (int nt = 0; nt < 4; ++nt) {
                const int col = wid * 64 + nt * 16 + rl;
                unsigned short* base = H1 + (mt * 8 + (col >> 5)) * 512 +
                                       ((col >> 3) & 3) * 128 + g * 32 + (col & 7);
                #pragma unroll
                for (int r = 0; r < 4; ++r)
                    base[r * 8] = f2bf(fmaxf(acc1[mt][nt][r], 0.0f));
            }
        }
    }
    __syncthreads();

    // ================= e layer 2: 256 -> 128 =================
    f32x4 acc2[4][2];
    #pragma unroll
    for (int nt = 0; nt < 2; ++nt) {
        const float b = be2[wid * 32 + nt * 16 + rl];
        #pragma unroll
        for (int mt = 0; mt < 4; ++mt) acc2[mt][nt] = (f32x4){b, b, b, b};
    }
    for (int s2 = 0; s2 < 8; ++s2) {
        bf16x8 xfr[4];
        #pragma unroll
        for (int mt = 0; mt < 4; ++mt)
            xfr[mt] = *(const bf16x8*)(H1 + (mt * 8 + s2) * 512 + lane * 8);
        #pragma unroll
        for (int nt = 0; nt < 2; ++nt) {
            const bf16x8 bfr = WFRAG(176 + s2 * 8 + nt * 4 + wid);
            #pragma unroll
            for (int mt = 0; mt < 4; ++mt)
                acc2[mt][nt] = __builtin_amdgcn_mfma_f32_16x16x32_bf16(xfr[mt], bfr, acc2[mt][nt], 0, 0, 0);
        }
        if (s2 < 7) ADV(22 + s2);   // ADV(28) stages chunk 30 (e3)
    }
    __syncthreads();   // all H1 reads done; drains chunk-30 staging

    // H2 fragment writes (relu); split regions (mt0,1 -> [32768), mt2,3 -> [57344))
    {
        #pragma unroll
        for (int mt = 0; mt < 4; ++mt) {
            const int h2b = (mt < 2) ? (16384 + mt * 2048) : (28672 + (mt - 2) * 2048);
            #pragma unroll
            for (int nt = 0; nt < 2; ++nt) {
                const int c2 = nt * 16 + rl;
                unsigned short* base = SM16 + h2b + wid * 512 +
                                       ((c2 >> 3) & 3) * 128 + g * 32 + (c2 & 7);
                #pragma unroll
                for (int r = 0; r < 4; ++r)
                    base[r * 8] = f2bf(fmaxf(acc2[mt][nt][r], 0.0f));
            }
        }
    }
    __syncthreads();

    // ================= e layer 3: 128 -> 18 (+log_softmax) =================
    {
        const int h2r = (wid < 2) ? (16384 + wid * 2048) : (28672 + (wid - 2) * 2048);
        f32x4 acc3[2];
        #pragma unroll
        for (int nt = 0; nt < 2; ++nt) {
            const int col = nt * 16 + rl;
            const float b = (col < NA) ? be3[col] : 0.0f;
            acc3[nt] = (f32x4){b, b, b, b};
        }
        #pragma unroll
        for (int s = 0; s < 4; ++s) {
            const bf16x8 af = *(const bf16x8*)(SM16 + h2r + s * 512 + lane * 8);
            #pragma unroll
            for (int nt = 0; nt < 2; ++nt) {
                const bf16x8 bfr = WFRAG(240 + s * 2 + nt);
                acc3[nt] = __builtin_amdgcn_mfma_f32_16x16x32_bf16(af, bfr, acc3[nt], 0, 0, 0);
            }
        }
        const bool v1 = (rl < 2);
        #pragma unroll
        for (int r = 0; r < 4; ++r) {
            const int p3 = wid * 16 + g * 4 + r;
            float x0 = acc3[0][r];
            float x1 = acc3[1][r];
            float m = fmaxf(x0, v1 ? x1 : -3.0e38f);
            m = fmaxf(m, __shfl_xor(m, 1)); m = fmaxf(m, __shfl_xor(m, 2));
            m = fmaxf(m, __shfl_xor(m, 4)); m = fmaxf(m, __shfl_xor(m, 8));
            float sm = expf(x0 - m) + (v1 ? expf(x1 - m) : 0.0f);
            sm += __shfl_xor(sm, 1); sm += __shfl_xor(sm, 2);
            sm += __shfl_xor(sm, 4); sm += __shfl_xor(sm, 8);
            const float L = m + logf(sm);
            if (p3 < NPCH) {
                float* o = out_each + (size_t)(img * NPCH + p3) * NA;
                o[rl] = x0 - L;
                if (v1) o[16 + rl] = x1 - L;
            }
        }
    }
#undef WFRAG
#undef STAGE
#undef ADV
#undef A1_STEP
}

// ---------------------------------------------------------------------------
// Kernel B: one wave per batch element (unchanged, validated).
// ---------------------------------------------------------------------------
__global__ __launch_bounds__(64)
void alpha_combine_kernel(const float* __restrict__ ws_alpha,
                          const float* __restrict__ out_each,
                          float* __restrict__ out_probs,
                          float* __restrict__ ws_ent)
{
    const int b = blockIdx.x;
    const int lane = threadIdx.x;

    float lg = (lane < NPCH) ? ws_alpha[b * NPCH + lane] : -3.0e38f;
    float m = lg;
    #pragma unroll
    for (int off = 32; off > 0; off >>= 1) m = fmaxf(m, __shfl_xor(m, off, 64));
    float ex = (lane < NPCH) ? expf(lg - m) : 0.0f;
    float s = ex;
    #pragma unroll
    for (int off = 32; off > 0; off >>= 1) s += __shfl_xor(s, off, 64);
    const float ls = logf(s);
    const float alpha = ex / s;

    float ent = (lane < NPCH) ? alpha * (lg - m - ls) : 0.0f;
    #pragma unroll
    for (int off = 32; off > 0; off >>= 1) ent += __shfl_xor(ent, off, 64);
    if (lane == 0) ws_ent[b] = ent;

    float acc = 0.0f;
    const float* eb = out_each + (size_t)b * NPCH * NA;
    for (int p = 0; p < NPCH; ++p) {
        const float ap = __shfl(alpha, p, 64);
        if (lane < NA) acc += ap * eb[p * NA + lane];
    }
    float mm = (lane < NA) ? acc : -3.0e38f;
    #pragma unroll
    for (int off = 32; off > 0; off >>= 1) mm = fmaxf(mm, __shfl_xor(mm, off, 64));
    float ee = (lane < NA) ? expf(acc - mm) : 0.0f;
    #pragma unroll
    for (int off = 32; off > 0; off >>= 1) ee += __shfl_xor(ee, off, 64);
    if (lane < NA) out_probs[b * NA + lane] = acc - mm - logf(ee);
}

__global__ __launch_bounds__(256)
void ent_reduce_kernel(const float* __restrict__ ws_ent, float* __restrict__ out_scalar)
{
    float s = 0.0f;
    for (int i = threadIdx.x; i < NB; i += 256) s += ws_ent[i];
    #pragma unroll
    for (int off = 32; off > 0; off >>= 1) s += __shfl_xor(s, off, 64);
    __shared__ float ps[4];
    if ((threadIdx.x & 63) == 0) ps[threadIdx.x >> 6] = s;
    __syncthreads();
    if (threadIdx.x == 0)
        out_scalar[0] = (ps[0] + ps[1] + ps[2] + ps[3]) * (1.0f / NB);
}

extern "C" void kernel_launch(void* const* d_in, const int* in_sizes, int n_in,
                              void* d_out, int out_size, void* d_ws, size_t ws_size,
                              hipStream_t stream)
{
    (void)in_sizes; (void)n_in; (void)out_size; (void)ws_size;

    const float* last_s = (const float*)d_in[0];
    const float* now_s  = (const float*)d_in[1];
    const float* We1 = (const float*)d_in[2];  const float* be1 = (const float*)d_in[3];
    const float* We2 = (const float*)d_in[4];  const float* be2 = (const float*)d_in[5];
    const float* We3 = (const float*)d_in[6];  const float* be3 = (const float*)d_in[7];
    const float* Wa1 = (const float*)d_in[8];  const float* ba1 = (const float*)d_in[9];
    const float* Wa2 = (const float*)d_in[10]; const float* ba2 = (const float*)d_in[11];
    const float* Wa3 = (const float*)d_in[12]; const float* ba3 = (const float*)d_in[13];

    float* out = (float*)d_out;
    float* out_probs = out;                    // [B,18]
    float* out_ent   = out + NB * NA;          // scalar
    float* out_each  = out + NB * NA + 1;      // [B,49,18]

    float* ws_alpha = (float*)d_ws;            // [TOTAL]
    float* ws_ent   = ws_alpha + TOTAL;        // [NB]
    unsigned short* wst = (unsigned short*)(ws_ent + NB);  // weight stream (256KB)

    prep_weights<<<dim3((WS_US + 255) / 256), dim3(256), 0, stream>>>(
        We1, We2, We3, Wa1, Wa2, wst);

    fused_mfma_kernel<<<dim3(NB), dim3(256), 0, stream>>>(
        last_s, now_s, wst, be1, be2, be3, ba1, ba2, ba3, Wa3,
        out_each, ws_alpha);

    alpha_combine_kernel<<<dim3(NB), dim3(64), 0, stream>>>(
        ws_alpha, out_each, out_probs, ws_ent);

    ent_reduce_kernel<<<dim3(1), dim3(256), 0, stream>>>(ws_ent, out_ent);
}

// Round 6
// 253.225 us; speedup vs baseline: 2.7466x; 1.5808x over previous
//
#include <hip/hip_runtime.h>
#include <math.h>

#define NPCH 49
#define NA 18
#define NB 8192
#define TOTAL (NB*NPCH)    // 401408

typedef __attribute__((ext_vector_type(8))) short bf16x8;
typedef __attribute__((ext_vector_type(4))) float f32x4;

__device__ __forceinline__ unsigned short f2bf(float f) {
    unsigned int u = __float_as_uint(f);
    return (unsigned short)((u + 0x7FFFu + ((u >> 16) & 1u)) >> 16);
}

#define MF(a,b,c) __builtin_amdgcn_mfma_f32_16x16x32_bf16((a),(b),(c),0,0,0)
// Raw barrier: waits only LDS ops, leaves global register prefetches in flight.
#define RAWBAR() do { \
    asm volatile("s_waitcnt lgkmcnt(0)" ::: "memory"); \
    __builtin_amdgcn_s_barrier(); \
    asm volatile("" ::: "memory"); \
} while (0)

// ---------------------------------------------------------------------------
// Weight stream (UNCHANGED from validated R5): 256 frags x 512 ushort, chunk
// order = consumption order. Frag fs element (l,j) = W[k0+(l>>4)*8+j][n0+(l&15)]
//  fs   0..19 : a1   s=fs>>2, w=fs&3   (k<144 ? Wa1 : 0)
//  fs  20..27 : a2   s=(fs-20)>>2, w=&3
//  fs  32..175: e1   q=fs-32: s=q>>4, nt=(q>>2)&3, w=q&3
//  fs 176..239: e2   q=fs-176: s=q>>3, nt=(q>>2)&1, w=q&3
//  fs 240..247: e3   q=fs-240: s=q>>1, nt=q&1 (n>=18 -> 0)
// ---------------------------------------------------------------------------
#define WS_US (256*512)

__global__ __launch_bounds__(256)
void prep_weights(const float* __restrict__ We1, const float* __restrict__ We2,
                  const float* __restrict__ We3, const float* __restrict__ Wa1,
                  const float* __restrict__ Wa2, unsigned short* __restrict__ wst)
{
    int i = blockIdx.x * 256 + threadIdx.x;
    if (i >= WS_US) return;
    const int fs = i >> 9, l = (i >> 3) & 63, j = i & 7;
    const int kh = ((l >> 4) << 3) + j;
    const int nl = l & 15;
    float v = 0.0f;
    if (fs < 20) {
        int s = fs >> 2, w = fs & 3;
        int k = s * 32 + kh, n = w * 16 + nl;
        v = (k < 144) ? Wa1[k * 64 + n] : 0.0f;
    } else if (fs < 28) {
        int q = fs - 20, s = q >> 2, w = q & 3;
        v = Wa2[(s * 32 + kh) * 64 + (w * 16 + nl)];
    } else if (fs < 32) {
        v = 0.0f;
    } else if (fs < 176) {
        int q = fs - 32, s = q >> 4, nt = (q >> 2) & 3, w = q & 3;
        v = We1[(s * 32 + kh) * 256 + (w * 64 + nt * 16 + nl)];
    } else if (fs < 240) {
        int q = fs - 176, s = q >> 3, nt = (q >> 2) & 1, w = q & 3;
        v = We2[(s * 32 + kh) * 128 + (w * 32 + nt * 16 + nl)];
    } else if (fs < 248) {
        int q = fs - 240, s = q >> 1, nt = q & 1;
        int n = nt * 16 + nl;
        v = (n < NA) ? We3[(s * 32 + kh) * NA + n] : 0.0f;
    }
    wst[i] = f2bf(v);
}

// ---------------------------------------------------------------------------
// Fused kernel: 1 block = 1 image, 4 waves, N-split MFMA phases. Weights are
// global->REGISTER loads (L2-resident stream, 3-buffer rotation; compiler
// tracks deps). Only 7 raw barriers (cross-wave LDS handoffs).
// LDS (46080 B, 3 blocks/CU):
//   Ein  [0,36864)  9 k-slots x 4 mt (image staged DIRECTLY in frag layout)
//   H1   [0,32768)  overlays Ein after e1 | H2 [0,16384) overlays H1 after e2
//   HA1  [36864,45056) | APT [45056,46080)
// ---------------------------------------------------------------------------
__global__ __launch_bounds__(256, 3)
void fused_mfma_kernel(const float* __restrict__ last_s, const float* __restrict__ now_s,
                       const unsigned short* __restrict__ wstream,
                       const float* __restrict__ be1, const float* __restrict__ be2,
                       const float* __restrict__ be3, const float* __restrict__ ba1,
                       const float* __restrict__ ba2, const float* __restrict__ ba3,
                       const float* __restrict__ Wa3,
                       float* __restrict__ out_each, float* __restrict__ ws_alpha)
{
    __shared__ __align__(16) unsigned char smem[46080];
    unsigned short* Ein = (unsigned short*)smem;            // [4mt][9s][512]
    unsigned short* H1  = (unsigned short*)smem;            // [4mt][8s][512] overlay
    unsigned short* H2  = (unsigned short*)smem;            // [4mt][4s][512] overlay
    unsigned short* HA1 = (unsigned short*)(smem + 36864);  // [4mt][2s][512]
    float*          APT = (float*)(smem + 45056);           // [4][64]

    const int t    = threadIdx.x;
    const int lane = t & 63;
    const int wid  = t >> 6;
    const int g    = lane >> 4;
    const int rl   = lane & 15;
    const int img  = blockIdx.x;

#define GFRAG(fs) (*(const bf16x8*)(wstream + (size_t)(fs) * 512 + lane * 8))

    // ---- prefetch alpha + first e1 weight frags (fly during image staging) ----
    bf16x8 wa1f[5], wa2f[2];
    #pragma unroll
    for (int s = 0; s < 5; ++s) wa1f[s] = GFRAG(s * 4 + wid);
    #pragma unroll
    for (int s = 0; s < 2; ++s) wa2f[s] = GFRAG(20 + s * 4 + wid);
    bf16x8 wA[4], wB[4], wC[4];
    #pragma unroll
    for (int nt = 0; nt < 4; ++nt) wA[nt] = GFRAG(32 + 0 * 16 + nt * 4 + wid);
    #pragma unroll
    for (int nt = 0; nt < 4; ++nt) wB[nt] = GFRAG(32 + 1 * 16 + nt * 4 + wid);
    #pragma unroll
    for (int nt = 0; nt < 4; ++nt) wC[nt] = GFRAG(32 + 2 * 16 + nt * 4 + wid);

    // ---- phase 0: coalesced image read -> Ein fragment layout directly ----
    // Each float4 covers 4 pixels of ONE patch, features f..f+3 (f%4==0), so
    // diff and now each land as one aligned 8B ds_write.
    {
        const float* nowI  = now_s  + (size_t)img * 7056;
        const float* lastI = last_s + (size_t)img * 7056;
        #pragma unroll
        for (int it = 0; it < 7; ++it) {
            const int i = t + it * 256;
            if (i < 1764) {
                const float4 n4 = *(const float4*)(nowI + i * 4);
                const float4 l4 = *(const float4*)(lastI + i * 4);
                const int px = i * 4, row = px / 84, col = px - row * 84;
                const int pi = row / 12, fr = row - pi * 12;
                const int pj = col / 12, fc = col - pj * 12;
                const int p = pi * 7 + pj, f = fr * 12 + fc;
                const int wp = p >> 4, rp = p & 15;
                const float k255 = 1.0f / 255.0f;
                ushort4 d4, w4;
                d4.x = f2bf((n4.x - l4.x) * k255); d4.y = f2bf((n4.y - l4.y) * k255);
                d4.z = f2bf((n4.z - l4.z) * k255); d4.w = f2bf((n4.w - l4.w) * k255);
                w4.x = f2bf(n4.x * k255); w4.y = f2bf(n4.y * k255);
                w4.z = f2bf(n4.z * k255); w4.w = f2bf(n4.w * k255);
                const int s1 = f >> 5, g1 = (f >> 3) & 3, j1 = f & 7;
                *(ushort4*)(Ein + (wp * 9 + s1) * 512 + g1 * 128 + rp * 8 + j1) = d4;
                const int k2 = 144 + f;
                const int s2 = k2 >> 5, g2 = (k2 >> 3) & 3, j2 = k2 & 7;
                *(ushort4*)(Ein + (wp * 9 + s2) * 512 + g2 * 128 + rp * 8 + j2) = w4;
            }
        }
    }
    RAWBAR();   // B1: Ein ready (rows 49..63 unstaged: all consumers row-local + guarded)

    // ================= alpha layer 1: 144(->160) -> 64 =================
    const int colA = wid * 16 + rl;
    f32x4 accA[4];
    {
        const float b1 = ba1[colA];
        #pragma unroll
        for (int mt = 0; mt < 4; ++mt) accA[mt] = (f32x4){b1, b1, b1, b1};
        #pragma unroll
        for (int sa = 0; sa < 5; ++sa) {
            int ok = 144 + sa * 32 + g * 8;
            if (ok > 280) ok = 280;   // k>=288 tail: weight rows are zero; clamp into valid data
            #pragma unroll
            for (int mt = 0; mt < 4; ++mt) {
                const bf16x8 af = *(const bf16x8*)(Ein + (mt * 9 + (ok >> 5)) * 512 +
                                                   ((ok >> 3) & 3) * 128 + rl * 8);
                accA[mt] = MF(af, wa1f[sa], accA[mt]);
            }
        }
        const int sA  = wid >> 1;
        const int hiA = (wid & 1) * 2 + (rl >> 3);
        const int jA  = rl & 7;
        #pragma unroll
        for (int mt = 0; mt < 4; ++mt) {
            unsigned short* base = HA1 + (mt * 2 + sA) * 512 + hiA * 128 + g * 32 + jA;
            #pragma unroll
            for (int r = 0; r < 4; ++r)
                base[r * 8] = f2bf(fmaxf(accA[mt][r], 0.0f));
        }
    }
    RAWBAR();   // B2: HA1 ready

    // ================= alpha layer 2 + fused layer 3 =================
    {
        const float b2 = ba2[colA];
        const float w3 = Wa3[colA];
        f32x4 accB[4];
        #pragma unroll
        for (int mt = 0; mt < 4; ++mt) accB[mt] = (f32x4){b2, b2, b2, b2};
        #pragma unroll
        for (int s = 0; s < 2; ++s) {
            #pragma unroll
            for (int mt = 0; mt < 4; ++mt) {
                const bf16x8 af = *(const bf16x8*)(HA1 + (mt * 2 + s) * 512 + lane * 8);
                accB[mt] = MF(af, wa2f[s], accB[mt]);
            }
        }
        #pragma unroll
        for (int mt = 0; mt < 4; ++mt) {
            #pragma unroll
            for (int r = 0; r < 4; ++r) {
                float v = fmaxf(accB[mt][r], 0.0f) * w3;
                v += __shfl_xor(v, 1); v += __shfl_xor(v, 2);
                v += __shfl_xor(v, 4); v += __shfl_xor(v, 8);
                if (rl == 0) APT[wid * 64 + mt * 16 + g * 4 + r] = v;
            }
        }
    }
    RAWBAR();   // B3: APT ready
    if (t < NPCH)
        ws_alpha[img * NPCH + t] = APT[t] + APT[64 + t] + APT[128 + t] + APT[192 + t] + ba3[0];

    // ================= e layer 1: 288 -> 256 (3-buffer weight rotation) =================
    f32x4 acc1[4][4];
    #pragma unroll
    for (int nt = 0; nt < 4; ++nt) {
        const float b = be1[wid * 64 + nt * 16 + rl];
        #pragma unroll
        for (int mt = 0; mt < 4; ++mt) acc1[mt][nt] = (f32x4){b, b, b, b};
    }

#define E1_STEP(W, s, sn) do { \
    const bf16x8 x0_ = *(const bf16x8*)(Ein + (0 * 9 + (s)) * 512 + lane * 8); \
    const bf16x8 x1_ = *(const bf16x8*)(Ein + (1 * 9 + (s)) * 512 + lane * 8); \
    const bf16x8 x2_ = *(const bf16x8*)(Ein + (2 * 9 + (s)) * 512 + lane * 8); \
    const bf16x8 x3_ = *(const bf16x8*)(Ein + (3 * 9 + (s)) * 512 + lane * 8); \
    _Pragma("unroll") \
    for (int nt = 0; nt < 4; ++nt) { \
        acc1[0][nt] = MF(x0_, W[nt], acc1[0][nt]); \
        acc1[1][nt] = MF(x1_, W[nt], acc1[1][nt]); \
        acc1[2][nt] = MF(x2_, W[nt], acc1[2][nt]); \
        acc1[3][nt] = MF(x3_, W[nt], acc1[3][nt]); \
    } \
    if ((sn) <= 8) { \
        _Pragma("unroll") \
        for (int nt = 0; nt < 4; ++nt) W[nt] = GFRAG(32 + (sn) * 16 + nt * 4 + wid); \
    } \
} while (0)

    E1_STEP(wA, 0, 3); E1_STEP(wB, 1, 4); E1_STEP(wC, 2, 5);
    E1_STEP(wA, 3, 6); E1_STEP(wB, 4, 7); E1_STEP(wC, 5, 8);
    E1_STEP(wA, 6, 9); E1_STEP(wB, 7, 9); E1_STEP(wC, 8, 9);
#undef E1_STEP

    RAWBAR();   // B4: all Ein reads done -> H1 may overlay

    // H1 fragment writes (relu)
    #pragma unroll
    for (int mt = 0; mt < 4; ++mt) {
        #pragma unroll
        for (int nt = 0; nt < 4; ++nt) {
            const int col = wid * 64 + nt * 16 + rl;
            unsigned short* base = H1 + (mt * 8 + (col >> 5)) * 512 +
                                   ((col >> 3) & 3) * 128 + g * 32 + (col & 7);
            #pragma unroll
            for (int r = 0; r < 4; ++r)
                base[r * 8] = f2bf(fmaxf(acc1[mt][nt][r], 0.0f));
        }
    }
    RAWBAR();   // B5: H1 ready

    // ================= e layer 2: 256 -> 128 =================
    f32x4 acc2[4][2];
    #pragma unroll
    for (int nt = 0; nt < 2; ++nt) {
        const float b = be2[wid * 32 + nt * 16 + rl];
        #pragma unroll
        for (int mt = 0; mt < 4; ++mt) acc2[mt][nt] = (f32x4){b, b, b, b};
    }
    bf16x8 vA[2], vB[2], vC[2];
    #pragma unroll
    for (int nt = 0; nt < 2; ++nt) vA[nt] = GFRAG(176 + 0 * 8 + nt * 4 + wid);
    #pragma unroll
    for (int nt = 0; nt < 2; ++nt) vB[nt] = GFRAG(176 + 1 * 8 + nt * 4 + wid);
    #pragma unroll
    for (int nt = 0; nt < 2; ++nt) vC[nt] = GFRAG(176 + 2 * 8 + nt * 4 + wid);

#define E2_STEP(V, s2, sn) do { \
    const bf16x8 x0_ = *(const bf16x8*)(H1 + (0 * 8 + (s2)) * 512 + lane * 8); \
    const bf16x8 x1_ = *(const bf16x8*)(H1 + (1 * 8 + (s2)) * 512 + lane * 8); \
    const bf16x8 x2_ = *(const bf16x8*)(H1 + (2 * 8 + (s2)) * 512 + lane * 8); \
    const bf16x8 x3_ = *(const bf16x8*)(H1 + (3 * 8 + (s2)) * 512 + lane * 8); \
    _Pragma("unroll") \
    for (int nt = 0; nt < 2; ++nt) { \
        acc2[0][nt] = MF(x0_, V[nt], acc2[0][nt]); \
        acc2[1][nt] = MF(x1_, V[nt], acc2[1][nt]); \
        acc2[2][nt] = MF(x2_, V[nt], acc2[2][nt]); \
        acc2[3][nt] = MF(x3_, V[nt], acc2[3][nt]); \
    } \
    if ((sn) <= 7) { \
        _Pragma("unroll") \
        for (int nt = 0; nt < 2; ++nt) V[nt] = GFRAG(176 + (sn) * 8 + nt * 4 + wid); \
    } \
} while (0)

    E2_STEP(vA, 0, 3); E2_STEP(vB, 1, 4); E2_STEP(vC, 2, 5);
    E2_STEP(vA, 3, 6); E2_STEP(vB, 4, 7); E2_STEP(vC, 5, 8);
    E2_STEP(vA, 6, 8); E2_STEP(vB, 7, 8);
#undef E2_STEP

    // e3 weight frags (replicated; in flight across the barriers)
    bf16x8 w3f[8];
    #pragma unroll
    for (int q = 0; q < 8; ++q) w3f[q] = GFRAG(240 + q);

    RAWBAR();   // B6: all H1 reads done -> H2 may overlay

    // H2 fragment writes (relu)
    #pragma unroll
    for (int mt = 0; mt < 4; ++mt) {
        #pragma unroll
        for (int nt = 0; nt < 2; ++nt) {
            const int c2 = nt * 16 + rl;
            unsigned short* base = H2 + (mt * 4 + wid) * 512 +
                                   ((c2 >> 3) & 3) * 128 + g * 32 + (c2 & 7);
            #pragma unroll
            for (int r = 0; r < 4; ++r)
                base[r * 8] = f2bf(fmaxf(acc2[mt][nt][r], 0.0f));
        }
    }
    RAWBAR();   // B7: H2 ready

    // ================= e layer 3: 128 -> 18 (+log_softmax) =================
    {
        f32x4 acc3[2];
        #pragma unroll
        for (int nt = 0; nt < 2; ++nt) {
            const int col = nt * 16 + rl;
            const float b = (col < NA) ? be3[col] : 0.0f;
            acc3[nt] = (f32x4){b, b, b, b};
        }
        #pragma unroll
        for (int s = 0; s < 4; ++s) {
            const bf16x8 af = *(const bf16x8*)(H2 + (wid * 4 + s) * 512 + lane * 8);
            acc3[0] = MF(af, w3f[s * 2 + 0], acc3[0]);
            acc3[1] = MF(af, w3f[s * 2 + 1], acc3[1]);
        }
        const bool v1 = (rl < 2);
        #pragma unroll
        for (int r = 0; r < 4; ++r) {
            const int p3 = wid * 16 + g * 4 + r;
            float x0 = acc3[0][r];
            float x1 = acc3[1][r];
            float m = fmaxf(x0, v1 ? x1 : -3.0e38f);
            m = fmaxf(m, __shfl_xor(m, 1)); m = fmaxf(m, __shfl_xor(m, 2));
            m = fmaxf(m, __shfl_xor(m, 4)); m = fmaxf(m, __shfl_xor(m, 8));
            float sm = expf(x0 - m) + (v1 ? expf(x1 - m) : 0.0f);
            sm += __shfl_xor(sm, 1); sm += __shfl_xor(sm, 2);
            sm += __shfl_xor(sm, 4); sm += __shfl_xor(sm, 8);
            const float L = m + logf(sm);
            if (p3 < NPCH) {
                float* o = out_each + (size_t)(img * NPCH + p3) * NA;
                o[rl] = x0 - L;
                if (v1) o[16 + rl] = x1 - L;
            }
        }
    }
#undef GFRAG
}

// ---------------------------------------------------------------------------
// Kernel B: one wave per batch element (unchanged, validated).
// ---------------------------------------------------------------------------
__global__ __launch_bounds__(64)
void alpha_combine_kernel(const float* __restrict__ ws_alpha,
                          const float* __restrict__ out_each,
                          float* __restrict__ out_probs,
                          float* __restrict__ ws_ent)
{
    const int b = blockIdx.x;
    const int lane = threadIdx.x;

    float lg = (lane < NPCH) ? ws_alpha[b * NPCH + lane] : -3.0e38f;
    float m = lg;
    #pragma unroll
    for (int off = 32; off > 0; off >>= 1) m = fmaxf(m, __shfl_xor(m, off, 64));
    float ex = (lane < NPCH) ? expf(lg - m) : 0.0f;
    float s = ex;
    #pragma unroll
    for (int off = 32; off > 0; off >>= 1) s += __shfl_xor(s, off, 64);
    const float ls = logf(s);
    const float alpha = ex / s;

    float ent = (lane < NPCH) ? alpha * (lg - m - ls) : 0.0f;
    #pragma unroll
    for (int off = 32; off > 0; off >>= 1) ent += __shfl_xor(ent, off, 64);
    if (lane == 0) ws_ent[b] = ent;

    float acc = 0.0f;
    const float* eb = out_each + (size_t)b * NPCH * NA;
    for (int p = 0; p < NPCH; ++p) {
        const float ap = __shfl(alpha, p, 64);
        if (lane < NA) acc += ap * eb[p * NA + lane];
    }
    float mm = (lane < NA) ? acc : -3.0e38f;
    #pragma unroll
    for (int off = 32; off > 0; off >>= 1) mm = fmaxf(mm, __shfl_xor(mm, off, 64));
    float ee = (lane < NA) ? expf(acc - mm) : 0.0f;
    #pragma unroll
    for (int off = 32; off > 0; off >>= 1) ee += __shfl_xor(ee, off, 64);
    if (lane < NA) out_probs[b * NA + lane] = acc - mm - logf(ee);
}

__global__ __launch_bounds__(256)
void ent_reduce_kernel(const float* __restrict__ ws_ent, float* __restrict__ out_scalar)
{
    float s = 0.0f;
    for (int i = threadIdx.x; i < NB; i += 256) s += ws_ent[i];
    #pragma unroll
    for (int off = 32; off > 0; off >>= 1) s += __shfl_xor(s, off, 64);
    __shared__ float ps[4];
    if ((threadIdx.x & 63) == 0) ps[threadIdx.x >> 6] = s;
    __syncthreads();
    if (threadIdx.x == 0)
        out_scalar[0] = (ps[0] + ps[1] + ps[2] + ps[3]) * (1.0f / NB);
}

extern "C" void kernel_launch(void* const* d_in, const int* in_sizes, int n_in,
                              void* d_out, int out_size, void* d_ws, size_t ws_size,
                              hipStream_t stream)
{
    (void)in_sizes; (void)n_in; (void)out_size; (void)ws_size;

    const float* last_s = (const float*)d_in[0];
    const float* now_s  = (const float*)d_in[1];
    const float* We1 = (const float*)d_in[2];  const float* be1 = (const float*)d_in[3];
    const float* We2 = (const float*)d_in[4];  const float* be2 = (const float*)d_in[5];
    const float* We3 = (const float*)d_in[6];  const float* be3 = (const float*)d_in[7];
    const float* Wa1 = (const float*)d_in[8];  const float* ba1 = (const float*)d_in[9];
    const float* Wa2 = (const float*)d_in[10]; const float* ba2 = (const float*)d_in[11];
    const float* Wa3 = (const float*)d_in[12]; const float* ba3 = (const float*)d_in[13];

    float* out = (float*)d_out;
    float* out_probs = out;                    // [B,18]
    float* out_ent   = out + NB * NA;          // scalar
    float* out_each  = out + NB * NA + 1;      // [B,49,18]

    float* ws_alpha = (float*)d_ws;            // [TOTAL]
    float* ws_ent   = ws_alpha + TOTAL;        // [NB]
    unsigned short* wst = (unsigned short*)(ws_ent + NB);  // weight stream (256KB)

    prep_weights<<<dim3((WS_US + 255) / 256), dim3(256), 0, stream>>>(
        We1, We2, We3, Wa1, Wa2, wst);

    fused_mfma_kernel<<<dim3(NB), dim3(256), 0, stream>>>(
        last_s, now_s, wst, be1, be2, be3, ba1, ba2, ba3, Wa3,
        out_each, ws_alpha);

    alpha_combine_kernel<<<dim3(NB), dim3(64), 0, stream>>>(
        ws_alpha, out_each, out_probs, ws_ent);

    ent_reduce_kernel<<<dim3(1), dim3(256), 0, stream>>>(ws_ent, out_ent);
}